// Round 18
// baseline (402.257 us; speedup 1.0000x reference)
//
#include <hip/hip_runtime.h>

typedef _Float16 hfrag_t __attribute__((ext_vector_type(8)));   // 8 x f16 (4 VGPRs)
typedef _Float16 h2_t    __attribute__((ext_vector_type(2)));
typedef __attribute__((ext_vector_type(4))) float    f4_t;
typedef __attribute__((ext_vector_type(4))) unsigned u4_t;

#define LOG_2PI   1.8378770664093453f
#define TWO_LOG2  1.3862943611198906f
#define T_TILES   4            // 16-point tiles per wave (state in registers)
#define BLOCK     256          // 4 waves
#define PTS_BLK   256          // 4 waves * 4 tiles * 16 pts
#define ZCLAMP    30000.0f     // keeps h1 = w1*z inside f16 range

__device__ __forceinline__ h2_t pkh2(float a, float b) {
  return __builtin_bit_cast(h2_t, __builtin_amdgcn_cvt_pkrtz(a, b));  // v_cvt_pkrtz_f16_f32
}
__device__ __forceinline__ unsigned pku(float a, float b) {
  return __builtin_bit_cast(unsigned, pkh2(a, b));
}
// native packed leaky-relu: v_pk_mul_f16 + v_pk_max_f16
__device__ __forceinline__ h2_t leaky2(h2_t h) {
  h2_t t = h * (h2_t){(_Float16)0.01f, (_Float16)0.01f};
  return __builtin_elementwise_max(h, t);
}
__device__ __forceinline__ float dot2h(h2_t a, h2_t b, float c) {
  return __builtin_amdgcn_fdot2(a, b, c, false);
}

__global__ __launch_bounds__(BLOCK)
void ihll_kernel(
    const float* __restrict__ pred, const float* __restrict__ targ, const float* __restrict__ twp,
    const float* __restrict__ sW1, const float* __restrict__ sB1, const float* __restrict__ sW2,
    const float* __restrict__ sB2, const float* __restrict__ sW3, const float* __restrict__ sB3,
    const float* __restrict__ tW1, const float* __restrict__ tB1, const float* __restrict__ tW2,
    const float* __restrict__ tB2, const float* __restrict__ tW3, const float* __restrict__ tB3,
    float* __restrict__ out, int M) {
  // ZERO-BARRIER main loop: W2 A-frags are loaded per-pass straight from
  // global (L1/L2-resident 32KB/layer slice) -> no LDS weight staging, no
  // per-layer __syncthreads, no wave convoys. Only small tables live in LDS
  // (staged once; single barrier in the whole kernel). Flow state in regs.
  // Pad shapes LDS to ~37KB -> 4 blocks/CU -> allocator VGPR budget ~128.
  __shared__ unsigned c1h[6][2][32];      // 1.5KB half2(w1)
  __shared__ unsigned b1h[6][2][32];      // 1.5KB half2(b1)
  __shared__ unsigned w3h[6][2][4][8];    // 1.5KB [g][2n+j] half2(w3)
  __shared__ float    b2s[6][2][64];      // 3KB  b2 fp32 (MFMA C-init)
  __shared__ float    wsum[4];
  __shared__ float    pad[7548];          // ~29.5KB occupancy-shaping pad

  const int tid  = threadIdx.x;
  const int lane = tid & 63, wave = tid >> 6;
  const int pr   = lane & 15, g = lane >> 4;
  const int pbase = blockIdx.x * PTS_BLK;
  if (M == 0) pad[tid] = (float)tid;      // never true: keeps pad allocated

  // ---- stage per-layer small tables (all 6 layers, once) ----
  for (int idx = tid; idx < 384; idx += BLOCK) {       // c1h/b1h
    int i = idx >> 6, r = idx & 63, m = r >> 5, jp = r & 31;
    int jo = i & 1, jm = jo ^ 1;                       // MASK[i]: i even -> jm=1, jo=0
    const float* w1 = m ? tW1 : sW1;  const float* b1 = m ? tB1 : sB1;
    c1h[i][m][jp] = pku(w1[i * 128 + 4 * jp + jm], w1[i * 128 + 4 * jp + 2 + jm]);
    b1h[i][m][jp] = pku(b1[i * 64 + 2 * jp], b1[i * 64 + 2 * jp + 1]);
  }
  for (int idx = tid; idx < 384; idx += BLOCK) {       // w3h
    int i = idx >> 6, r = idx & 63, m = r >> 5, c = r & 31;
    int gg = c >> 3, c2 = c & 7, n = c2 >> 1, jj = c2 & 1;
    int jo = i & 1;
    const float* w3 = m ? tW3 : sW3;
    int row = 16 * n + 4 * gg + 2 * jj;
    w3h[i][m][gg][c2] = pku(w3[i * 128 + jo * 64 + row], w3[i * 128 + jo * 64 + row + 1]);
  }
  for (int idx = tid; idx < 768; idx += BLOCK) {       // b2s
    int i = idx >> 7, r = idx & 127, m = r >> 6, j = r & 63;
    const float* b2 = m ? tB2 : sB2;
    b2s[i][m][j] = b2[i * 64 + j];
  }

  // ---- per-lane register flow state (replicated over the 4 lane-groups) ----
  float z0[T_TILES], z1[T_TILES], ld[T_TILES], pre0[T_TILES];
  #pragma unroll
  for (int t = 0; t < T_TILES; ++t) {
    int P = pbase + wave * 64 + t * 16 + pr;
    float e0 = 0.f, e1 = 0.f;
    if (P < M) {
      float4 p4 = ((const float4*)pred)[P];
      float2 t2 = ((const float2*)targ)[P];
      float s0 = sqrtf(fabsf(p4.z)), s1 = sqrtf(fabsf(p4.w));
      e0 = (p4.x - t2.x) / (s0 + 1e-9f);
      e1 = (p4.y - t2.y) / (s1 + 1e-9f);
    }
    z0[t] = e0; z1[t] = e1; ld[t] = 0.f; pre0[t] = 0.f;
  }
  __syncthreads();   // the ONLY barrier before the epilogue

  // ---- layer loop: i = 5..0 — pure compute + cached global loads ----
  #pragma unroll 1
  for (int li = 0; li < 6; ++li) {
    const int i = 5 - li;
    const int jo = i & 1;             // component written this layer
    const bool upd0 = (jo == 0);      // jo==0: input comp is z1, output z0
    const float b3s = sB3[i * 2 + jo];
    const float b3t = tB3[i * 2 + jo];

    // masked-in input is the SAME for both nets: clamp+pack once per tile
    h2_t zz[T_TILES];
    #pragma unroll
    for (int t = 0; t < T_TILES; ++t) {
      float zin = upd0 ? z1[t] : z0[t];
      zin = fmaxf(fminf(zin, ZCLAMP), -ZCLAMP);
      zz[t] = pkh2(zin, zin);
    }

    // ---- two passes (compile-time m): m=0 s-net (pre0 in regs), m=1 t-net ----
    #pragma unroll
    for (int m = 0; m < 2; ++m) {
      // W2 A-frags straight from global (L1/L2-hot 16KB slice per net).
      // A-frag for mfma_f32_16x16x32_f16: lane holds A[16n+pr][32q+8g+e].
      const float* wsrc = (m ? tW2 : sW2) + i * 4096;
      u4_t af[8];
      #pragma unroll
      for (int f = 0; f < 8; ++f) {
        int n = f & 3, q = f >> 2;
        const float* s = wsrc + (16 * n + pr) * 64 + 32 * q + 8 * g;
        float4 a = *(const float4*)s;
        float4 b = *(const float4*)(s + 4);
        af[f] = (u4_t){pku(a.x, a.y), pku(a.z, a.w), pku(b.x, b.y), pku(b.z, b.w)};
      }
      h2_t c1q[8], b1q[8];
      *(u4_t*)&c1q[0] = *(const u4_t*)&c1h[i][m][4 * g];
      *(u4_t*)&c1q[4] = *(const u4_t*)&c1h[i][m][16 + 4 * g];
      *(u4_t*)&b1q[0] = *(const u4_t*)&b1h[i][m][4 * g];
      *(u4_t*)&b1q[4] = *(const u4_t*)&b1h[i][m][16 + 4 * g];
      h2_t w3q[8];
      *(u4_t*)&w3q[0] = *(const u4_t*)&w3h[i][m][g][0];
      *(u4_t*)&w3q[4] = *(const u4_t*)&w3h[i][m][g][4];
      f4_t b2q[4];
      #pragma unroll
      for (int n = 0; n < 4; ++n)
        b2q[n] = *(const f4_t*)&b2s[i][m][n * 16 + 4 * g];

      // ---- tile loop: fully unrolled, no LDS, no barriers ----
      #pragma unroll
      for (int t = 0; t < T_TILES; ++t) {
        f4_t acc[4];
        #pragma unroll
        for (int q = 0; q < 2; ++q) {
          h2_t hh[4];
          #pragma unroll
          for (int e = 0; e < 4; ++e)
            hh[e] = leaky2(c1q[q * 4 + e] * zz[t] + b1q[q * 4 + e]);  // v_pk_fma_f16
          hfrag_t B = __builtin_bit_cast(hfrag_t, hh);
          #pragma unroll
          for (int n = 0; n < 4; ++n) {
            f4_t c = (q == 0) ? b2q[n] : acc[n];   // b2 folded into first MFMA
            acc[n] = __builtin_amdgcn_mfma_f32_16x16x32_f16(
                __builtin_bit_cast(hfrag_t, af[q * 4 + n]), B, c, 0, 0, 0);
          }
        }
        // layer 3: leaky(h2) . w3, split (2-deep) dot chains
        float pa_ = 0.f, pb_ = 0.f;
        #pragma unroll
        for (int n = 0; n < 4; ++n) {
          h2_t a01 = leaky2(pkh2(acc[n][0], acc[n][1]));
          h2_t a23 = leaky2(pkh2(acc[n][2], acc[n][3]));
          if (n < 2) {
            pa_ = dot2h(a01, w3q[2 * n], pa_);
            pa_ = dot2h(a23, w3q[2 * n + 1], pa_);
          } else {
            pb_ = dot2h(a01, w3q[2 * n], pb_);
            pb_ = dot2h(a23, w3q[2 * n + 1], pb_);
          }
        }
        float pt = pa_ + pb_;
        pt += __shfl_xor(pt, 16);
        pt += __shfl_xor(pt, 32);      // all 64 lanes hold the full sum

        if (m == 0) {
          pre0[t] = pt;                // register hand-off to the t-net pass
        } else {
          // coupling update computed identically by ALL lanes
          float sv = 1.f - 2.f / (__expf(2.f * (pre0[t] + b3s)) + 1.f);  // tanh
          float tv = pt + b3t;
          float zo = upd0 ? z0[t] : z1[t];
          float zn = (zo - tv) * __expf(-sv);
          if (upd0) z0[t] = zn; else z1[t] = zn;
          ld[t] -= sv;
        }
      }
    }
  }

  // ---- epilogue: recompute base term from global, add prior + logdet ----
  float csum = 0.f;
  #pragma unroll
  for (int t = 0; t < T_TILES; ++t) {
    int P = pbase + wave * 64 + t * 16 + pr;
    if (P < M) {
      float4 p4 = ((const float4*)pred)[P];
      float2 t2 = ((const float2*)targ)[P];
      float w   = twp[P];
      float s0 = sqrtf(fabsf(p4.z)), s1 = sqrtf(fabsf(p4.w));
      float e0 = (p4.x - t2.x) / (s0 + 1e-9f);
      float e1 = (p4.y - t2.y) / (s1 + 1e-9f);
      float bs = 2.f * (logf(s0) + logf(s1)) + TWO_LOG2 + fabsf(e0) + fabsf(e1);
      float prior = -0.5f * (z0[t] * z0[t] + z1[t] * z1[t]) - LOG_2PI;
      float lphi  = prior + ld[t];
      csum += (bs - 2.f * lphi) * w;
    }
  }
  // butterfly over all 64 lanes (4 group-copies of each point -> /4 later)
  #pragma unroll
  for (int off = 1; off <= 32; off <<= 1)
    csum += __shfl_xor(csum, off);
  if (lane == 0) wsum[wave] = csum;
  __syncthreads();
  if (tid == 0) {
    float tot = wsum[0] + wsum[1] + wsum[2] + wsum[3];
    atomicAdd(out, tot * (1.0f / 32768.0f));   // /4 replication, /8192 batch
  }
}

extern "C" void kernel_launch(void* const* d_in, const int* in_sizes, int n_in,
                              void* d_out, int out_size, void* d_ws, size_t ws_size,
                              hipStream_t stream) {
  const float* pred = (const float*)d_in[0];
  const float* targ = (const float*)d_in[1];
  const float* twp  = (const float*)d_in[2];
  const float* sW1 = (const float*)d_in[3];  const float* sB1 = (const float*)d_in[4];
  const float* sW2 = (const float*)d_in[5];  const float* sB2 = (const float*)d_in[6];
  const float* sW3 = (const float*)d_in[7];  const float* sB3 = (const float*)d_in[8];
  const float* tW1 = (const float*)d_in[9];  const float* tB1 = (const float*)d_in[10];
  const float* tW2 = (const float*)d_in[11]; const float* tB2 = (const float*)d_in[12];
  const float* tW3 = (const float*)d_in[13]; const float* tB3 = (const float*)d_in[14];

  const int M = in_sizes[2];               // N*K points
  const int blocks = (M + PTS_BLK - 1) / PTS_BLK;

  hipMemsetAsync(d_out, 0, sizeof(float), stream);
  hipLaunchKernelGGL(ihll_kernel, dim3(blocks), dim3(BLOCK), 0, stream,
                     pred, targ, twp, sW1, sB1, sW2, sB2, sW3, sB3,
                     tW1, tB1, tW2, tB2, tW3, tB3, (float*)d_out, M);
}

// Round 19
// 224.423 us; speedup vs baseline: 1.7924x; 1.7924x over previous
//
#include <hip/hip_runtime.h>

typedef _Float16 hfrag_t __attribute__((ext_vector_type(8)));   // 8 x f16 (4 VGPRs)
typedef _Float16 h2_t    __attribute__((ext_vector_type(2)));
typedef __attribute__((ext_vector_type(4))) float    f4_t;
typedef __attribute__((ext_vector_type(4))) unsigned u4_t;

#define LOG_2PI   1.8378770664093453f
#define TWO_LOG2  1.3862943611198906f
#define T_TILES   8            // 16-point tiles per wave
#define BLOCK     256          // 4 waves
#define PTS_BLK   512          // 4 waves * 8 tiles * 16 pts
#define ZCLAMP    30000.0f     // keeps h1 = w1*z inside f16 range; only clips tanh-saturated pts

__device__ __forceinline__ unsigned pkh(float a, float b) {
  return __builtin_bit_cast(unsigned, __builtin_amdgcn_cvt_pkrtz(a, b));
}
__device__ __forceinline__ unsigned pk_fma_h(unsigned a, unsigned b, unsigned c) {
  unsigned d;
  asm("v_pk_fma_f16 %0, %1, %2, %3" : "=v"(d) : "v"(a), "v"(b), "v"(c));
  return d;
}
__device__ __forceinline__ unsigned pk_add_h(unsigned a, unsigned b) {
  unsigned d;
  asm("v_pk_add_f16 %0, %1, %2" : "=v"(d) : "v"(a), "v"(b));
  return d;
}
// packed leaky-relu: max(h, 0.01h) on 2 f16 lanes (2 insts)
__device__ __forceinline__ unsigned pk_leaky_h(unsigned h, unsigned k01) {
  unsigned t, r;
  asm("v_pk_mul_f16 %0, %1, %2" : "=v"(t) : "v"(h), "v"(k01));
  asm("v_pk_max_f16 %0, %1, %2" : "=v"(r) : "v"(h), "v"(t));
  return r;
}
__device__ __forceinline__ float dot2h(unsigned a, unsigned b, float c) {
  return __builtin_amdgcn_fdot2(__builtin_bit_cast(h2_t, a), __builtin_bit_cast(h2_t, b), c, false);
}

// Stage one layer's W2 (both MLPs) into LDS as f16 MFMA A-fragments.
// A-frag layout for mfma_f32_16x16x32_f16: lane l holds A[16n + (l&15)][32q + 8*(l>>4) + e], e=0..7
__device__ __forceinline__ void stage_layer(u4_t* afr, const float* sW2, const float* tW2,
                                            int layer, int tid) {
  #pragma unroll
  for (int it = 0; it < 4; ++it) {
    int idx = tid + it * BLOCK;          // 0..1023
    int l = idx & 63, f = (idx >> 6) & 7, m = (idx >> 9) & 1;
    int n = f & 3, q = f >> 2;
    int row = 16 * n + (l & 15), kb = 32 * q + 8 * (l >> 4);
    const float* src = (m ? tW2 : sW2) + layer * 4096 + row * 64 + kb;
    float4 a = *(const float4*)src;
    float4 b = *(const float4*)(src + 4);
    afr[(m * 8 + f) * 64 + l] =
        (u4_t){pkh(a.x, a.y), pkh(a.z, a.w), pkh(b.x, b.y), pkh(b.z, b.w)};
  }
}

__global__ __launch_bounds__(BLOCK)
__attribute__((amdgpu_waves_per_eu(2)))   // min-only: permit up to ~256 VGPR, no force
void ihll_kernel(
    const float* __restrict__ pred, const float* __restrict__ targ, const float* __restrict__ twp,
    const float* __restrict__ sW1, const float* __restrict__ sB1, const float* __restrict__ sW2,
    const float* __restrict__ sB2, const float* __restrict__ sW3, const float* __restrict__ sB3,
    const float* __restrict__ tW1, const float* __restrict__ tB1, const float* __restrict__ tW2,
    const float* __restrict__ tB2, const float* __restrict__ tW3, const float* __restrict__ tB3,
    float* __restrict__ out, int M) {
  __shared__ u4_t     afr[2 * 8 * 64];     // 16KB f16 W2 A-frags
  __shared__ float4   zld[PTS_BLK];        // 8KB  (z0, z1, ldet, pad)
  __shared__ float    pre0v[PTS_BLK];      // 2KB  s-net preact (m=0 -> m=1, wave-private)
  __shared__ unsigned c1h[6][2][32];       // 1.5KB half2(w1)
  __shared__ unsigned b1h[6][2][32];       // 1.5KB half2(b1)
  __shared__ unsigned w3h[6][2][4][8];     // 1.5KB [g][2n+j]: half2 of w3 rows 16n+4g+2j..+1
  __shared__ float    b2s[6][2][64];       // 3KB  b2 fp32 (MFMA C-init)
  __shared__ float    wsum[4];

  const int tid  = threadIdx.x;
  const int lane = tid & 63, wave = tid >> 6;
  const int pr   = lane & 15, g = lane >> 4;
  const int pbase = blockIdx.x * PTS_BLK;
  const unsigned k01h = pkh(0.01f, 0.01f);

  // ---- stage per-layer small tables (all 6 layers, once) ----
  for (int idx = tid; idx < 384; idx += BLOCK) {       // c1h/b1h
    int i = idx >> 6, r = idx & 63, m = r >> 5, jp = r & 31;
    int jo = i & 1, jm = jo ^ 1;                       // MASK[i]: i even -> jm=1, jo=0
    const float* w1 = m ? tW1 : sW1;  const float* b1 = m ? tB1 : sB1;
    c1h[i][m][jp] = pkh(w1[i * 128 + 4 * jp + jm], w1[i * 128 + 4 * jp + 2 + jm]);
    b1h[i][m][jp] = pkh(b1[i * 64 + 2 * jp], b1[i * 64 + 2 * jp + 1]);
  }
  for (int idx = tid; idx < 384; idx += BLOCK) {       // w3h
    int i = idx >> 6, r = idx & 63, m = r >> 5, c = r & 31;
    int gg = c >> 3, c2 = c & 7, n = c2 >> 1, jj = c2 & 1;
    int jo = i & 1;
    const float* w3 = m ? tW3 : sW3;
    int row = 16 * n + 4 * gg + 2 * jj;
    w3h[i][m][gg][c2] = pkh(w3[i * 128 + jo * 64 + row], w3[i * 128 + jo * 64 + row + 1]);
  }
  for (int idx = tid; idx < 768; idx += BLOCK) {       // b2s
    int i = idx >> 7, r = idx & 127, m = r >> 6, j = r & 63;
    const float* b2 = m ? tB2 : sB2;
    b2s[i][m][j] = b2[i * 64 + j];
  }
  // ---- stage point state: z = error (base term recomputed in epilogue) ----
  #pragma unroll
  for (int it = 0; it < 2; ++it) {
    int idx = tid + it * BLOCK;
    int P = pbase + idx;
    float4 zs = make_float4(0.f, 0.f, 0.f, 0.f);
    if (P < M) {
      float4 p4 = ((const float4*)pred)[P];
      float2 t2 = ((const float2*)targ)[P];
      float s0 = sqrtf(fabsf(p4.z)), s1 = sqrtf(fabsf(p4.w));
      zs.x = (p4.x - t2.x) / (s0 + 1e-9f);
      zs.y = (p4.y - t2.y) / (s1 + 1e-9f);
    }
    zld[idx] = zs;
  }
  stage_layer(afr, sW2, tW2, 5, tid);   // first layer processed is i=5
  __syncthreads();

  const int wbase = wave * (T_TILES * 16);

  // ---- layer loop: i = 5..0 ----
  #pragma unroll 1
  for (int li = 0; li < 6; ++li) {
    const int i = 5 - li;
    const int jo = i & 1;             // component written this layer
    const bool upd0 = (jo == 0);      // jo==0: input comp is z1, output z0
    const float b3s = sB3[i * 2 + jo];
    const float b3t = tB3[i * 2 + jo];

    // ---- two passes (compile-time m): m=0 s-net, m=1 t-net + coupling ----
    #pragma unroll
    for (int m = 0; m < 2; ++m) {
      u4_t af[8];
      #pragma unroll
      for (int f = 0; f < 8; ++f)
        af[f] = afr[(m * 8 + f) * 64 + lane];
      unsigned c1q[8], b1q[8];
      *(u4_t*)&c1q[0] = *(const u4_t*)&c1h[i][m][4 * g];
      *(u4_t*)&c1q[4] = *(const u4_t*)&c1h[i][m][16 + 4 * g];
      *(u4_t*)&b1q[0] = *(const u4_t*)&b1h[i][m][4 * g];
      *(u4_t*)&b1q[4] = *(const u4_t*)&b1h[i][m][16 + 4 * g];
      unsigned w3q[8];
      *(u4_t*)&w3q[0] = *(const u4_t*)&w3h[i][m][g][0];
      *(u4_t*)&w3q[4] = *(const u4_t*)&w3h[i][m][g][4];
      f4_t b2q[4];
      #pragma unroll
      for (int n = 0; n < 4; ++n)
        b2q[n] = *(const f4_t*)&b2s[i][m][n * 16 + 4 * g];

      // === 4-tile groups: 4 independent chains, constants shared ===
      #pragma unroll 1
      for (int tt = 0; tt < T_TILES / 4; ++tt) {
        const int w0 = wbase + (4 * tt) * 16 + pr;
        float4 zv0 = zld[w0];
        float4 zv1 = zld[w0 + 16];
        float4 zv2 = zld[w0 + 32];
        float4 zv3 = zld[w0 + 48];
        float zi0 = upd0 ? zv0.y : zv0.x;
        float zi1 = upd0 ? zv1.y : zv1.x;
        float zi2 = upd0 ? zv2.y : zv2.x;
        float zi3 = upd0 ? zv3.y : zv3.x;
        zi0 = fmaxf(fminf(zi0, ZCLAMP), -ZCLAMP);
        zi1 = fmaxf(fminf(zi1, ZCLAMP), -ZCLAMP);
        zi2 = fmaxf(fminf(zi2, ZCLAMP), -ZCLAMP);
        zi3 = fmaxf(fminf(zi3, ZCLAMP), -ZCLAMP);
        const unsigned zz0 = pkh(zi0, zi0), zz1 = pkh(zi1, zi1);
        const unsigned zz2 = pkh(zi2, zi2), zz3 = pkh(zi3, zi3);

        f4_t acc0[4], acc1[4], acc2[4], acc3[4];
        #pragma unroll
        for (int q = 0; q < 2; ++q) {
          unsigned h0[4], h1v[4], h2v[4], h3[4];
          #pragma unroll
          for (int e = 0; e < 4; ++e) {
            h0[e]  = pk_leaky_h(pk_fma_h(c1q[q * 4 + e], zz0, b1q[q * 4 + e]), k01h);
            h1v[e] = pk_leaky_h(pk_fma_h(c1q[q * 4 + e], zz1, b1q[q * 4 + e]), k01h);
            h2v[e] = pk_leaky_h(pk_fma_h(c1q[q * 4 + e], zz2, b1q[q * 4 + e]), k01h);
            h3[e]  = pk_leaky_h(pk_fma_h(c1q[q * 4 + e], zz3, b1q[q * 4 + e]), k01h);
          }
          hfrag_t B0 = __builtin_bit_cast(hfrag_t, (u4_t){h0[0], h0[1], h0[2], h0[3]});
          hfrag_t B1 = __builtin_bit_cast(hfrag_t, (u4_t){h1v[0], h1v[1], h1v[2], h1v[3]});
          hfrag_t B2 = __builtin_bit_cast(hfrag_t, (u4_t){h2v[0], h2v[1], h2v[2], h2v[3]});
          hfrag_t B3 = __builtin_bit_cast(hfrag_t, (u4_t){h3[0], h3[1], h3[2], h3[3]});
          #pragma unroll
          for (int n = 0; n < 4; ++n) {
            hfrag_t A = __builtin_bit_cast(hfrag_t, af[q * 4 + n]);
            acc0[n] = __builtin_amdgcn_mfma_f32_16x16x32_f16(A, B0, (q == 0) ? b2q[n] : acc0[n], 0, 0, 0);
            acc1[n] = __builtin_amdgcn_mfma_f32_16x16x32_f16(A, B1, (q == 0) ? b2q[n] : acc1[n], 0, 0, 0);
            acc2[n] = __builtin_amdgcn_mfma_f32_16x16x32_f16(A, B2, (q == 0) ? b2q[n] : acc2[n], 0, 0, 0);
            acc3[n] = __builtin_amdgcn_mfma_f32_16x16x32_f16(A, B3, (q == 0) ? b2q[n] : acc3[n], 0, 0, 0);
          }
        }
        // layer 3: leaky(h2).w3 with split (2-deep) dot chains per tile
        float p0a = 0.f, p0b = 0.f, p1a = 0.f, p1b = 0.f;
        float p2a = 0.f, p2b = 0.f, p3a = 0.f, p3b = 0.f;
        #pragma unroll
        for (int n = 0; n < 4; ++n) {
          unsigned a01 = pk_leaky_h(pkh(acc0[n][0], acc0[n][1]), k01h);
          unsigned a23 = pk_leaky_h(pkh(acc0[n][2], acc0[n][3]), k01h);
          unsigned b01 = pk_leaky_h(pkh(acc1[n][0], acc1[n][1]), k01h);
          unsigned b23 = pk_leaky_h(pkh(acc1[n][2], acc1[n][3]), k01h);
          unsigned c01 = pk_leaky_h(pkh(acc2[n][0], acc2[n][1]), k01h);
          unsigned c23 = pk_leaky_h(pkh(acc2[n][2], acc2[n][3]), k01h);
          unsigned d01 = pk_leaky_h(pkh(acc3[n][0], acc3[n][1]), k01h);
          unsigned d23 = pk_leaky_h(pkh(acc3[n][2], acc3[n][3]), k01h);
          if (n < 2) {
            p0a = dot2h(a01, w3q[2 * n], p0a);  p0a = dot2h(a23, w3q[2 * n + 1], p0a);
            p1a = dot2h(b01, w3q[2 * n], p1a);  p1a = dot2h(b23, w3q[2 * n + 1], p1a);
            p2a = dot2h(c01, w3q[2 * n], p2a);  p2a = dot2h(c23, w3q[2 * n + 1], p2a);
            p3a = dot2h(d01, w3q[2 * n], p3a);  p3a = dot2h(d23, w3q[2 * n + 1], p3a);
          } else {
            p0b = dot2h(a01, w3q[2 * n], p0b);  p0b = dot2h(a23, w3q[2 * n + 1], p0b);
            p1b = dot2h(b01, w3q[2 * n], p1b);  p1b = dot2h(b23, w3q[2 * n + 1], p1b);
            p2b = dot2h(c01, w3q[2 * n], p2b);  p2b = dot2h(c23, w3q[2 * n + 1], p2b);
            p3b = dot2h(d01, w3q[2 * n], p3b);  p3b = dot2h(d23, w3q[2 * n + 1], p3b);
          }
        }
        float pt0 = p0a + p0b, pt1 = p1a + p1b, pt2 = p2a + p2b, pt3 = p3a + p3b;

        if (m == 0) {
          // s-net: packed f16 reduce (tanh saturates -> f16-safe)
          unsigned r01 = pkh(pt0, pt1), r23 = pkh(pt2, pt3);
          r01 = pk_add_h(r01, __shfl_xor(r01, 16));
          r23 = pk_add_h(r23, __shfl_xor(r23, 16));
          r01 = pk_add_h(r01, __shfl_xor(r01, 32));
          r23 = pk_add_h(r23, __shfl_xor(r23, 32));
          if (g == 0) {
            h2_t v01 = __builtin_bit_cast(h2_t, r01);
            h2_t v23 = __builtin_bit_cast(h2_t, r23);
            pre0v[w0]      = (float)v01[0];
            pre0v[w0 + 16] = (float)v01[1];
            pre0v[w0 + 32] = (float)v23[0];
            pre0v[w0 + 48] = (float)v23[1];
          }
        } else {
          // t-net: scalar f32 reduce (range safety), then coupling update
          pt0 += __shfl_xor(pt0, 16);  pt0 += __shfl_xor(pt0, 32);
          pt1 += __shfl_xor(pt1, 16);  pt1 += __shfl_xor(pt1, 32);
          pt2 += __shfl_xor(pt2, 16);  pt2 += __shfl_xor(pt2, 32);
          pt3 += __shfl_xor(pt3, 16);  pt3 += __shfl_xor(pt3, 32);
          float s0v = 1.f - 2.f / (__expf(2.f * (pre0v[w0]      + b3s)) + 1.f);
          float s1v = 1.f - 2.f / (__expf(2.f * (pre0v[w0 + 16] + b3s)) + 1.f);
          float s2v = 1.f - 2.f / (__expf(2.f * (pre0v[w0 + 32] + b3s)) + 1.f);
          float s3v = 1.f - 2.f / (__expf(2.f * (pre0v[w0 + 48] + b3s)) + 1.f);
          float zo0 = upd0 ? zv0.x : zv0.y;
          float zo1 = upd0 ? zv1.x : zv1.y;
          float zo2 = upd0 ? zv2.x : zv2.y;
          float zo3 = upd0 ? zv3.x : zv3.y;
          float zn0 = (zo0 - (pt0 + b3t)) * __expf(-s0v);
          float zn1 = (zo1 - (pt1 + b3t)) * __expf(-s1v);
          float zn2 = (zo2 - (pt2 + b3t)) * __expf(-s2v);
          float zn3 = (zo3 - (pt3 + b3t)) * __expf(-s3v);
          if (upd0) { zv0.x = zn0; zv1.x = zn1; zv2.x = zn2; zv3.x = zn3; }
          else      { zv0.y = zn0; zv1.y = zn1; zv2.y = zn2; zv3.y = zn3; }
          zv0.z -= s0v;  zv1.z -= s1v;  zv2.z -= s2v;  zv3.z -= s3v;
          if (g == 0) {
            zld[w0]      = zv0;
            zld[w0 + 16] = zv1;
            zld[w0 + 32] = zv2;
            zld[w0 + 48] = zv3;
          }
        }
      }
    }
    __syncthreads();
    if (li < 5) {
      stage_layer(afr, sW2, tW2, i - 1, tid);
      __syncthreads();
    }
  }

  // ---- epilogue: recompute base term from global, add prior + logdet, reduce ----
  float csum = 0.f;
  #pragma unroll
  for (int it = 0; it < 2; ++it) {
    int idx = tid + it * BLOCK;
    int P = pbase + idx;
    if (P < M) {
      float4 p4 = ((const float4*)pred)[P];
      float2 t2 = ((const float2*)targ)[P];
      float w   = twp[P];
      float s0 = sqrtf(fabsf(p4.z)), s1 = sqrtf(fabsf(p4.w));
      float e0 = (p4.x - t2.x) / (s0 + 1e-9f);
      float e1 = (p4.y - t2.y) / (s1 + 1e-9f);
      float bs = 2.f * (logf(s0) + logf(s1)) + TWO_LOG2 + fabsf(e0) + fabsf(e1);
      float4 zv = zld[idx];
      float prior = -0.5f * (zv.x * zv.x + zv.y * zv.y) - LOG_2PI;
      float lphi  = prior + zv.z;
      csum += (bs - 2.f * lphi) * w;
    }
  }
  #pragma unroll
  for (int off = 1; off <= 32; off <<= 1)
    csum += __shfl_xor(csum, off);
  if (lane == 0) wsum[wave] = csum;
  __syncthreads();
  if (tid == 0) {
    float tot = wsum[0] + wsum[1] + wsum[2] + wsum[3];
    atomicAdd(out, tot * (1.0f / 8192.0f));   // /pred.shape[0]
  }
}

extern "C" void kernel_launch(void* const* d_in, const int* in_sizes, int n_in,
                              void* d_out, int out_size, void* d_ws, size_t ws_size,
                              hipStream_t stream) {
  const float* pred = (const float*)d_in[0];
  const float* targ = (const float*)d_in[1];
  const float* twp  = (const float*)d_in[2];
  const float* sW1 = (const float*)d_in[3];  const float* sB1 = (const float*)d_in[4];
  const float* sW2 = (const float*)d_in[5];  const float* sB2 = (const float*)d_in[6];
  const float* sW3 = (const float*)d_in[7];  const float* sB3 = (const float*)d_in[8];
  const float* tW1 = (const float*)d_in[9];  const float* tB1 = (const float*)d_in[10];
  const float* tW2 = (const float*)d_in[11]; const float* tB2 = (const float*)d_in[12];
  const float* tW3 = (const float*)d_in[13]; const float* tB3 = (const float*)d_in[14];

  const int M = in_sizes[2];               // N*K points
  const int blocks = (M + PTS_BLK - 1) / PTS_BLK;

  hipMemsetAsync(d_out, 0, sizeof(float), stream);
  hipLaunchKernelGGL(ihll_kernel, dim3(blocks), dim3(BLOCK), 0, stream,
                     pred, targ, twp, sW1, sB1, sW2, sB2, sW3, sB3,
                     tW1, tB1, tW2, tB2, tW3, tB3, (float*)d_out, M);
}